// Round 4
// baseline (46.398 us; speedup 1.0000x reference)
//
#include <hip/hip_runtime.h>
#include <math.h>

#define LAMB    5.0f
#define LOG_2PI 1.837877066409345f
#define LOG_PI  1.144729885849400f
#define L2E     1.4426950408889634f
#define LN2     0.6931471805599453f

constexpr int HID = 100;
constexpr int KC  = 30;

typedef float v2f __attribute__((ext_vector_type(2)));
typedef float v4f __attribute__((ext_vector_type(4)));

__device__ __forceinline__ v2f splat2(float s) { return (v2f){s, s}; }
__device__ __forceinline__ v4f splat4(float s) { return (v4f){s, s, s, s}; }
__device__ __forceinline__ v2f fma2(v2f a, v2f b, v2f c) { return __builtin_elementwise_fma(a, b, c); }
__device__ __forceinline__ v4f fma4(v4f a, v4f b, v4f c) { return __builtin_elementwise_fma(a, b, c); }
__device__ __forceinline__ v2f max2(v2f a, v2f b) { return __builtin_elementwise_max(a, b); }
__device__ __forceinline__ v4f max4(v4f a, v4f b) { return __builtin_elementwise_max(a, b); }
__device__ __forceinline__ v2f lo2(v4f a) { return (v2f){a.x, a.y}; }
__device__ __forceinline__ v2f hi2(v4f a) { return (v2f){a.z, a.w}; }
__device__ __forceinline__ v4f cat2(v2f a, v2f b) { return __builtin_shufflevector(a, b, 0, 1, 2, 3); }

__device__ __forceinline__ v2f rcp2(v2f x)  { return (v2f){__builtin_amdgcn_rcpf(x.x), __builtin_amdgcn_rcpf(x.y)}; }
__device__ __forceinline__ v2f sqrt2(v2f x) { return (v2f){__builtin_amdgcn_sqrtf(x.x), __builtin_amdgcn_sqrtf(x.y)}; }
__device__ __forceinline__ v2f exp2v(v2f x) { return (v2f){__builtin_amdgcn_exp2f(x.x), __builtin_amdgcn_exp2f(x.y)}; }
__device__ __forceinline__ v2f lnv(v2f x)   { return (v2f){__builtin_amdgcn_logf(x.x), __builtin_amdgcn_logf(x.y)} * splat2(LN2); }
__device__ __forceinline__ float log_f(float x) { return __builtin_amdgcn_logf(x) * LN2; }

// ln(1+u), safe for tiny u; branchless
__device__ __forceinline__ float log1p_s(float u) {
    float big = log_f(1.0f + u);
    float sml = u * (1.0f - 0.5f * u);
    return (u > 1e-5f) ? big : sml;
}
__device__ __forceinline__ v2f log1p2(v2f u) { return (v2f){log1p_s(u.x), log1p_s(u.y)}; }

// softplus = max(v,0) + log1p(exp(-|v|))
__device__ __forceinline__ v2f softplus2(v2f v) {
    v2f av = (v2f){fabsf(v.x), fabsf(v.y)};
    v2f e  = exp2v(av * splat2(-L2E));
    return max2(v, splat2(0.f)) + log1p2(e);
}

// Lanczos g=5 lgamma, packed over 2. Valid x>0.
__device__ __forceinline__ v2f lgamma2(v2f x) {
    v2f ser = splat2(1.000000000190015f)
            + splat2(76.18009172947146f)    * rcp2(x + splat2(1.0f))
            - splat2(86.50532032941677f)    * rcp2(x + splat2(2.0f))
            + splat2(24.01409824083091f)    * rcp2(x + splat2(3.0f))
            - splat2(1.231739572450155f)    * rcp2(x + splat2(4.0f))
            + splat2(1.208650973866179e-3f) * rcp2(x + splat2(5.0f))
            - splat2(5.395239384953e-6f)    * rcp2(x + splat2(6.0f));
    v2f t = x + splat2(5.5f);
    return (x + splat2(0.5f)) * lnv(t) - t + lnv(splat2(2.5066282746310005f) * ser * rcp2(x));
}

// everything after the decoder MLP, for one sample
__device__ __forceinline__ float post_sample(v2f xv, v2f ev, v2f z, v2f zstd,
                                             v2f xmu, v2f df,
                                             const float* __restrict__ rbfc,
                                             v2f* scale_out)
{
    const float zz = z.x * z.x + z.y * z.y;
    const float u0 = -(LAMB * L2E) * zz;
    v2f a = splat2(0.f);
#pragma unroll 6
    for (int k = 0; k < KC; ++k) {
        v2f  kc  = *(const v2f*)&rbfc[8 * k];
        float kqu = rbfc[8 * k + 2] + u0;
        v2f  wm  = *(const v2f*)&rbfc[8 * k + 4];
        float arg = fmaf(kc.x, z.x, fmaf(kc.y, z.y, kqu));
        a = fma2(splat2(__builtin_amdgcn_exp2f(arg)), wm, a);
    }
    const v2f ia = a + splat2(1e-10f);     // inv_std
    *scale_out = rcp2(ia);

    // student-t log prob (uses inv_std directly)
    const v2f y    = (xv - xmu) * ia;
    const v2f u    = y * y * rcp2(df);
    const v2f dfp1 = df + splat2(1.0f);
    const v2f lpx  = lgamma2(splat2(0.5f) * dfp1) - lgamma2(splat2(0.5f) * df)
                   - splat2(0.5f) * (lnv(df) + splat2(LOG_PI)) + lnv(ia)
                   - splat2(0.5f) * dfp1 * log1p2(u);

    // KL; (z - zmu)/sigma == eps
    const v2f e2 = ev * ev;
    const v2f lz = lnv(zstd);
    const float kl = -0.5f * (e2.x + e2.y) - 0.5f * (lz.x + lz.y) + 0.5f * zz;

    return lpx.x + lpx.y - kl;
}

__global__ __launch_bounds__(256) void rbf_pre(const float* __restrict__ Cc,
                                               const float* __restrict__ Wc,
                                               float* __restrict__ rbfc)
{
    int k = threadIdx.x;
    if (k < KC) {
        float c0 = Cc[2 * k], c1 = Cc[2 * k + 1];
        rbfc[8 * k + 0] = 2.0f * LAMB * L2E * c0;
        rbfc[8 * k + 1] = 2.0f * LAMB * L2E * c1;
        rbfc[8 * k + 2] = -(LAMB * L2E) * (c0 * c0 + c1 * c1);
        rbfc[8 * k + 3] = 0.f;
        rbfc[8 * k + 4] = fmaxf(Wc[2 * k],     0.f);
        rbfc[8 * k + 5] = fmaxf(Wc[2 * k + 1], 0.f);
        rbfc[8 * k + 6] = 0.f;
        rbfc[8 * k + 7] = 0.f;
    }
}

__global__ __launch_bounds__(256) void vae_main(
    const float* __restrict__ x,    const float* __restrict__ eps,
    const float* __restrict__ emw1, const float* __restrict__ emb1,
    const float* __restrict__ emw2, const float* __restrict__ emb2,
    const float* __restrict__ esw1, const float* __restrict__ esb1,
    const float* __restrict__ esw2, const float* __restrict__ esb2,
    const float* __restrict__ dmw1, const float* __restrict__ dmb1,
    const float* __restrict__ dmw2, const float* __restrict__ dmb2,
    const float* __restrict__ dfw1, const float* __restrict__ dfb1,
    const float* __restrict__ dfw2, const float* __restrict__ dfb2,
    const float* __restrict__ rbfc,
    float* __restrict__ out_xmu,   float* __restrict__ out_scale,
    float* __restrict__ out_z,     float* __restrict__ out_zmu,
    float* __restrict__ out_zstd,  float* __restrict__ partial,
    int n)
{
    const int t = blockIdx.x * 256 + threadIdx.x;   // handles samples 2t, 2t+1

    float val = 0.0f;

    if (2 * t + 1 < n) {
        const v4f xq = *(const v4f*)&x[4 * t];
        const v4f eq = *(const v4f*)&eps[4 * t];
        const v2f xA = lo2(xq), xB = hi2(xq);
        const v2f eA = lo2(eq), eB = hi2(eq);

        // ---- encoder MLPs (mu, std) for both samples ----
        v2f amA = splat2(0.f), asA = splat2(0.f);
        v2f amB = splat2(0.f), asB = splat2(0.f);
        const v4f xA0 = splat4(xA.x), xA1 = splat4(xA.y);
        const v4f xB0 = splat4(xB.x), xB1 = splat4(xB.y);
#pragma unroll 5
        for (int j = 0; j < HID; j += 4) {
            // mu-MLP weights
            v4f w0 = *(const v4f*)&emw1[j];
            v4f w1 = *(const v4f*)&emw1[HID + j];
            v4f b  = *(const v4f*)&emb1[j];
            v4f hA = max4(fma4(xA0, w0, fma4(xA1, w1, b)), splat4(0.f));
            v4f hB = max4(fma4(xB0, w0, fma4(xB1, w1, b)), splat4(0.f));
            v4f c0 = *(const v4f*)&emw2[2 * j];
            v4f c1 = *(const v4f*)&emw2[2 * j + 4];
            amA = fma2(splat2(hA.x), lo2(c0), amA);
            amA = fma2(splat2(hA.y), hi2(c0), amA);
            amA = fma2(splat2(hA.z), lo2(c1), amA);
            amA = fma2(splat2(hA.w), hi2(c1), amA);
            amB = fma2(splat2(hB.x), lo2(c0), amB);
            amB = fma2(splat2(hB.y), hi2(c0), amB);
            amB = fma2(splat2(hB.z), lo2(c1), amB);
            amB = fma2(splat2(hB.w), hi2(c1), amB);
            // std-MLP weights
            v4f s0 = *(const v4f*)&esw1[j];
            v4f s1 = *(const v4f*)&esw1[HID + j];
            v4f sb = *(const v4f*)&esb1[j];
            v4f gA = max4(fma4(xA0, s0, fma4(xA1, s1, sb)), splat4(0.f));
            v4f gB = max4(fma4(xB0, s0, fma4(xB1, s1, sb)), splat4(0.f));
            v4f d0 = *(const v4f*)&esw2[2 * j];
            v4f d1 = *(const v4f*)&esw2[2 * j + 4];
            asA = fma2(splat2(gA.x), lo2(d0), asA);
            asA = fma2(splat2(gA.y), hi2(d0), asA);
            asA = fma2(splat2(gA.z), lo2(d1), asA);
            asA = fma2(splat2(gA.w), hi2(d1), asA);
            asB = fma2(splat2(gB.x), lo2(d0), asB);
            asB = fma2(splat2(gB.y), hi2(d0), asB);
            asB = fma2(splat2(gB.z), lo2(d1), asB);
            asB = fma2(splat2(gB.w), hi2(d1), asB);
        }
        const v2f eb2 = *(const v2f*)&emb2[0];
        const v2f sb2 = *(const v2f*)&esb2[0];
        const v2f zmuA  = amA + eb2,            zmuB  = amB + eb2;
        const v2f zstdA = softplus2(asA + sb2), zstdB = softplus2(asB + sb2);
        const v2f sigA  = sqrt2(zstdA),         sigB  = sqrt2(zstdB);
        const v2f zA    = fma2(sigA, eA, zmuA), zB    = fma2(sigB, eB, zmuB);

        // ---- decoder MLPs (mu, df) for both samples ----
        v2f dmA = splat2(0.f), dfA = splat2(0.f);
        v2f dmB = splat2(0.f), dfB = splat2(0.f);
        const v4f zA0 = splat4(zA.x), zA1 = splat4(zA.y);
        const v4f zB0 = splat4(zB.x), zB1 = splat4(zB.y);
#pragma unroll 5
        for (int j = 0; j < HID; j += 4) {
            v4f w0 = *(const v4f*)&dmw1[j];
            v4f w1 = *(const v4f*)&dmw1[HID + j];
            v4f b  = *(const v4f*)&dmb1[j];
            v4f hA = max4(fma4(zA0, w0, fma4(zA1, w1, b)), splat4(0.f));
            v4f hB = max4(fma4(zB0, w0, fma4(zB1, w1, b)), splat4(0.f));
            v4f c0 = *(const v4f*)&dmw2[2 * j];
            v4f c1 = *(const v4f*)&dmw2[2 * j + 4];
            dmA = fma2(splat2(hA.x), lo2(c0), dmA);
            dmA = fma2(splat2(hA.y), hi2(c0), dmA);
            dmA = fma2(splat2(hA.z), lo2(c1), dmA);
            dmA = fma2(splat2(hA.w), hi2(c1), dmA);
            dmB = fma2(splat2(hB.x), lo2(c0), dmB);
            dmB = fma2(splat2(hB.y), hi2(c0), dmB);
            dmB = fma2(splat2(hB.z), lo2(c1), dmB);
            dmB = fma2(splat2(hB.w), hi2(c1), dmB);

            v4f f0 = *(const v4f*)&dfw1[j];
            v4f f1 = *(const v4f*)&dfw1[HID + j];
            v4f fb = *(const v4f*)&dfb1[j];
            v4f gA = max4(fma4(zA0, f0, fma4(zA1, f1, fb)), splat4(0.f));
            v4f gB = max4(fma4(zB0, f0, fma4(zB1, f1, fb)), splat4(0.f));
            v4f d0 = *(const v4f*)&dfw2[2 * j];
            v4f d1 = *(const v4f*)&dfw2[2 * j + 4];
            dfA = fma2(splat2(gA.x), lo2(d0), dfA);
            dfA = fma2(splat2(gA.y), hi2(d0), dfA);
            dfA = fma2(splat2(gA.z), lo2(d1), dfA);
            dfA = fma2(splat2(gA.w), hi2(d1), dfA);
            dfB = fma2(splat2(gB.x), lo2(d0), dfB);
            dfB = fma2(splat2(gB.y), hi2(d0), dfB);
            dfB = fma2(splat2(gB.z), lo2(d1), dfB);
            dfB = fma2(splat2(gB.w), hi2(d1), dfB);
        }
        const v2f db2 = *(const v2f*)&dmb2[0];
        const v2f fb2 = *(const v2f*)&dfb2[0];
        const v2f xmuA = dmA + db2,            xmuB = dmB + db2;
        const v2f vdfA = softplus2(dfA + fb2), vdfB = softplus2(dfB + fb2);

        v2f scA, scB;
        const float vA = post_sample(xA, eA, zA, zstdA, xmuA, vdfA, rbfc, &scA);
        const float vB = post_sample(xB, eB, zB, zstdB, xmuB, vdfB, rbfc, &scB);
        val = vA + vB;

        // ---- outputs: float4 stores covering both samples ----
        *(v4f*)&out_xmu[4 * t]   = cat2(xmuA, xmuB);
        *(v4f*)&out_scale[4 * t] = cat2(scA, scB);
        *(v4f*)&out_z[4 * t]     = cat2(zA, zB);
        *(v4f*)&out_zmu[4 * t]   = cat2(zmuA, zmuB);
        *(v4f*)&out_zstd[4 * t]  = cat2(zstdA, zstdB);
    }

    // ---- deterministic block reduction of val ----
#pragma unroll
    for (int off = 32; off > 0; off >>= 1)
        val += __shfl_down(val, off, 64);

    __shared__ float wsum[4];
    const int lane = threadIdx.x & 63;
    const int wid  = threadIdx.x >> 6;
    if (lane == 0) wsum[wid] = val;
    __syncthreads();
    if (threadIdx.x == 0)
        partial[blockIdx.x] = (wsum[0] + wsum[1]) + (wsum[2] + wsum[3]);
}

__global__ __launch_bounds__(256) void vae_reduce(
    const float* __restrict__ partial, int nblk, float* __restrict__ out, int n)
{
    __shared__ double sh[256];
    double acc = 0.0;
    for (int i = threadIdx.x; i < nblk; i += 256) acc += (double)partial[i];
    sh[threadIdx.x] = acc;
    __syncthreads();
#pragma unroll
    for (int s = 128; s > 0; s >>= 1) {
        if (threadIdx.x < s) sh[threadIdx.x] += sh[threadIdx.x + s];
        __syncthreads();
    }
    if (threadIdx.x == 0) out[0] = (float)(sh[0] / (double)n);
}

extern "C" void kernel_launch(void* const* d_in, const int* in_sizes, int n_in,
                              void* d_out, int out_size, void* d_ws, size_t ws_size,
                              hipStream_t stream) {
    const float* x    = (const float*)d_in[0];
    const float* eps  = (const float*)d_in[1];
    const float* emw1 = (const float*)d_in[2];
    const float* emb1 = (const float*)d_in[3];
    const float* emw2 = (const float*)d_in[4];
    const float* emb2 = (const float*)d_in[5];
    const float* esw1 = (const float*)d_in[6];
    const float* esb1 = (const float*)d_in[7];
    const float* esw2 = (const float*)d_in[8];
    const float* esb2 = (const float*)d_in[9];
    const float* dmw1 = (const float*)d_in[10];
    const float* dmb1 = (const float*)d_in[11];
    const float* dmw2 = (const float*)d_in[12];
    const float* dmb2 = (const float*)d_in[13];
    const float* dfw1 = (const float*)d_in[14];
    const float* dfb1 = (const float*)d_in[15];
    const float* dfw2 = (const float*)d_in[16];
    const float* dfb2 = (const float*)d_in[17];
    const float* Cc   = (const float*)d_in[18];
    const float* Wc   = (const float*)d_in[19];

    const int n = in_sizes[0] / 2;      // N samples
    float* out = (float*)d_out;
    float* out_xmu   = out + 1;
    float* out_scale = out + 1 + 2 * (size_t)n;
    float* out_z     = out + 1 + 4 * (size_t)n;
    float* out_zmu   = out + 1 + 6 * (size_t)n;
    float* out_zstd  = out + 1 + 8 * (size_t)n;

    float* partial = (float*)d_ws;          // [nblk] floats
    float* rbfc    = (float*)d_ws + 1024;   // [8*KC] floats

    const int nthr = n / 2;                 // n is even (N = 524288)
    const int nblk = (nthr + 255) / 256;

    rbf_pre<<<1, 256, 0, stream>>>(Cc, Wc, rbfc);

    vae_main<<<nblk, 256, 0, stream>>>(
        x, eps,
        emw1, emb1, emw2, emb2,
        esw1, esb1, esw2, esb2,
        dmw1, dmb1, dmw2, dmb2,
        dfw1, dfb1, dfw2, dfb2,
        rbfc,
        out_xmu, out_scale, out_z, out_zmu, out_zstd,
        partial, n);

    vae_reduce<<<1, 256, 0, stream>>>(partial, nblk, out, n);
}